// Round 2
// baseline (3046.285 us; speedup 1.0000x reference)
//
#include <hip/hip_runtime.h>
#include <math.h>

#define NN 50000
#define NE 1000000

constexpr float kC121    = 2.1213203435596424f;
constexpr float kSqrt3   = 1.7320508075688772f;
constexpr float kInvSqrt2= 0.7071067811865475f;
constexpr float kInvSqrt8= 0.35355339059327373f;
constexpr float kInvSqrt3= 0.5773502691896258f;
constexpr float kInvSqrt5= 0.4472135954999579f;
constexpr float kSqrt2   = 1.4142135623730951f;
constexpr float kPi      = 3.14159265358979323846f;

__device__ __forceinline__ float swishf(float x){
    return x / (1.0f + __expf(-x));
}

// Transpose W1 (3x8x64 -> 3x64x8) and W2 (3x64x64 -> 3x64x64^T) so the
// per-edge MLP reads contiguous rows at wave-uniform addresses.
__global__ void transpose_w(const float* __restrict__ W1, const float* __restrict__ W2,
                            float* __restrict__ W1T, float* __restrict__ W2T){
    int i = blockIdx.x*blockDim.x + threadIdx.x;
    if (i < 3*8*64){
        int l = i/512, r = i%512; int k = r/64, j = r%64;
        W1T[l*512 + j*8 + k] = W1[i];
    }
    if (i < 3*64*64){
        int l = i/4096, r = i%4096; int k = r/64, j = r%64;
        W2T[l*4096 + j*64 + k] = W2[i];
    }
}

__global__ void edge_geom(const float* __restrict__ pos,
                          const int* __restrict__ snd,
                          const int* __restrict__ rcv,
                          float* __restrict__ nhat,
                          float* __restrict__ radial){
    int e = blockIdx.x*blockDim.x + threadIdx.x;
    if (e >= NE) return;
    int s = snd[e], r = rcv[e];
    float vx = pos[r*3+0]-pos[s*3+0];
    float vy = pos[r*3+1]-pos[s*3+1];
    float vz = pos[r*3+2]-pos[s*3+2];
    float len = sqrtf(vx*vx+vy*vy+vz*vz);
    float safe = (len==0.f)?1.f:len;
    float inv = 1.f/safe;
    nhat[e*3+0]=vx*inv; nhat[e*3+1]=vy*inv; nhat[e*3+2]=vz*inv;
    float x = len;
    float x2=x*x, x3=x2*x, x6=x3*x3, x7=x6*x, x8=x7*x;
    float poly = 1.f - 28.f*x6 + 48.f*x7 - 21.f*x8;
    float env = (x<1.f)?poly:0.f;
    float c = kSqrt2*env*inv;
    #pragma unroll
    for (int k=1;k<=8;k++){
        float b = sinf(kPi*(float)k*len)*c;
        radial[e*8+k-1] = (len==0.f)?0.f:b;
    }
}

__global__ void node_init(const float* __restrict__ nf,
                          float* __restrict__ s, float* __restrict__ v){
    int n = blockIdx.x*blockDim.x + threadIdx.x;
    if (n >= NN) return;
    s[n] = nf[n*7];
    #pragma unroll
    for (int i=0;i<6;i++) v[n*6+i] = nf[n*7+1+i];
}

__global__ void node_pre(const float* __restrict__ s, const float* __restrict__ v,
                         const float* __restrict__ Wss, const float* __restrict__ Wsv,
                         const float* __restrict__ Wus, const float* __restrict__ Wuv,
                         float* __restrict__ s_sc, float* __restrict__ v_sc,
                         float* __restrict__ su, float* __restrict__ vu,
                         float* __restrict__ aggs, float* __restrict__ aggv){
    int n = blockIdx.x*blockDim.x + threadIdx.x;
    if (n >= NN) return;
    float sv = s[n];
    float vv[6];
    #pragma unroll
    for (int i=0;i<6;i++) vv[i] = v[n*6+i];
    #pragma unroll
    for (int i=0;i<3;i++) s_sc[n*3+i] = sv*Wss[i];
    #pragma unroll
    for (int k=0;k<2;k++)
        #pragma unroll
        for (int c=0;c<3;c++)
            v_sc[n*6+k*3+c] = (vv[c]*Wsv[0*2+k] + vv[3+c]*Wsv[1*2+k]) * kInvSqrt2;
    su[n] = sv * Wus[0];
    #pragma unroll
    for (int k=0;k<2;k++)
        #pragma unroll
        for (int c=0;c<3;c++)
            vu[n*6+k*3+c] = (vv[c]*Wuv[0*2+k] + vv[3+c]*Wuv[1*2+k]) * kInvSqrt2;
    #pragma unroll
    for (int i=0;i<3;i++) aggs[n*3+i] = 0.f;
    #pragma unroll
    for (int i=0;i<15;i++) aggv[n*15+i] = 0.f;
}

__global__ void __launch_bounds__(256) edge_msg(
    const int* __restrict__ snd, const int* __restrict__ rcv,
    const float* __restrict__ nhat, const float* __restrict__ radial,
    const float* __restrict__ su, const float* __restrict__ vu,
    const float* __restrict__ W1T, const float* __restrict__ W2T,
    const float* __restrict__ W3,
    float* __restrict__ aggs, float* __restrict__ aggv){
    int e = blockIdx.x*blockDim.x + threadIdx.x;
    if (e >= NE) return;

    float rad[8];
    #pragma unroll
    for (int k=0;k<8;k++) rad[k] = radial[e*8+k];

    // stage 1: h1 = swish(rad @ W1 / sqrt8)   (W1T rows contiguous, uniform)
    float h1[64];
    #pragma unroll
    for (int j=0;j<64;j++){
        const float* w = W1T + j*8;
        float acc = rad[0]*w[0]+rad[1]*w[1]+rad[2]*w[2]+rad[3]*w[3]
                  + rad[4]*w[4]+rad[5]*w[5]+rad[6]*w[6]+rad[7]*w[7];
        h1[j] = swishf(acc*kInvSqrt8);
    }

    // stage 2+3: mix = (swish(h1 @ W2 / 8)) @ W3 / 8, streamed over j
    float mix[8] = {0.f,0.f,0.f,0.f,0.f,0.f,0.f,0.f};
    #pragma unroll 4
    for (int j=0;j<64;j++){
        const float* w = W2T + j*64;
        float acc = 0.f;
        #pragma unroll
        for (int k=0;k<64;k++) acc += h1[k]*w[k];
        float h2 = swishf(acc*0.125f);
        const float* w3 = W3 + j*8;
        #pragma unroll
        for (int m=0;m<8;m++) mix[m] += h2*w3[m];
    }
    #pragma unroll
    for (int m=0;m<8;m++) mix[m] *= 0.125f;

    int sn = snd[e], rn = rcv[e];
    float se = su[sn];
    float ve[6];
    #pragma unroll
    for (int i=0;i<6;i++) ve[i] = vu[sn*6+i];
    float nh[3];
    #pragma unroll
    for (int c=0;c<3;c++) nh[c] = nhat[e*3+c];
    float vd0 = ve[0]*nh[0]+ve[1]*nh[1]+ve[2]*nh[2];
    float vd1 = ve[3]*nh[0]+ve[4]*nh[1]+ve[5]*nh[2];

    atomicAdd(&aggs[rn*3+0], se *mix[0]);
    atomicAdd(&aggs[rn*3+1], vd0*mix[1]);
    atomicAdd(&aggs[rn*3+2], vd1*mix[2]);

    #pragma unroll
    for (int c=0;c<3;c++){
        atomicAdd(&aggv[rn*15+0 +c], ve[c]*mix[3]);
        atomicAdd(&aggv[rn*15+3 +c], ve[3+c]*mix[4]);
        atomicAdd(&aggv[rn*15+6 +c], kC121*(vd0*nh[c]-ve[c]*(1.f/3.f))*mix[5]);
        atomicAdd(&aggv[rn*15+9 +c], kC121*(vd1*nh[c]-ve[3+c]*(1.f/3.f))*mix[6]);
        atomicAdd(&aggv[rn*15+12+c], kSqrt3*se*nh[c]*mix[7]);
    }
}

__global__ void node_post(const float* __restrict__ aggs, const float* __restrict__ aggv,
                          const float* __restrict__ Wds, const float* __restrict__ Wdv,
                          const float* __restrict__ s_sc, const float* __restrict__ v_sc,
                          float* __restrict__ s, float* __restrict__ v,
                          float* __restrict__ out, int is_last){
    int n = blockIdx.x*blockDim.x + threadIdx.x;
    if (n >= NN) return;
    float as[3];
    #pragma unroll
    for (int j=0;j<3;j++) as[j] = aggs[n*3+j];
    float st[3];
    #pragma unroll
    for (int i=0;i<3;i++)
        st[i] = (as[0]*Wds[0*3+i]+as[1]*Wds[1*3+i]+as[2]*Wds[2*3+i])*kInvSqrt3 + s_sc[n*3+i];
    float vt[6];
    #pragma unroll
    for (int k=0;k<2;k++)
        #pragma unroll
        for (int c=0;c<3;c++){
            float acc = 0.f;
            #pragma unroll
            for (int m=0;m<5;m++) acc += aggv[n*15+m*3+c]*Wdv[m*2+k];
            vt[k*3+c] = acc*kInvSqrt5 + v_sc[n*6+k*3+c];
        }
    float snew = swishf(st[0]);
    float g1 = swishf(st[1]), g2 = swishf(st[2]);
    s[n] = snew;
    #pragma unroll
    for (int c=0;c<3;c++){
        float v0 = vt[c]*g1;
        float v1 = vt[3+c]*g2;
        v[n*6+c]   = v0;
        v[n*6+3+c] = v1;
        if (is_last) out[n*3+c] = v0;
    }
}

extern "C" void kernel_launch(void* const* d_in, const int* in_sizes, int n_in,
                              void* d_out, int out_size, void* d_ws, size_t ws_size,
                              hipStream_t stream){
    const float* pos = (const float*)d_in[0];
    const float* nf  = (const float*)d_in[1];
    const int*   snd = (const int*)d_in[2];
    const int*   rcv = (const int*)d_in[3];
    const float* Wss = (const float*)d_in[4];
    const float* Wsv = (const float*)d_in[5];
    const float* Wus = (const float*)d_in[6];
    const float* Wuv = (const float*)d_in[7];
    const float* W1  = (const float*)d_in[8];
    const float* W2  = (const float*)d_in[9];
    const float* W3  = (const float*)d_in[10];
    const float* Wds = (const float*)d_in[11];
    const float* Wdv = (const float*)d_in[12];
    float* out = (float*)d_out;

    float* p = (float*)d_ws;
    float* nhat   = p; p += (size_t)NE*3;
    float* radial = p; p += (size_t)NE*8;
    float* s      = p; p += NN;
    float* v      = p; p += NN*6;
    float* s_sc   = p; p += NN*3;
    float* v_sc   = p; p += NN*6;
    float* su     = p; p += NN;
    float* vu     = p; p += NN*6;
    float* aggs   = p; p += NN*3;
    float* aggv   = p; p += NN*15;
    float* W1T    = p; p += 3*512;
    float* W2T    = p; p += 3*4096;

    dim3 blk(256);
    transpose_w<<<dim3((3*4096+255)/256), blk, 0, stream>>>(W1, W2, W1T, W2T);
    edge_geom<<<dim3((NE+255)/256), blk, 0, stream>>>(pos, snd, rcv, nhat, radial);
    node_init<<<dim3((NN+255)/256), blk, 0, stream>>>(nf, s, v);
    for (int l=0;l<3;l++){
        node_pre<<<dim3((NN+255)/256), blk, 0, stream>>>(
            s, v, Wss+l*3, Wsv+l*4, Wus+l, Wuv+l*4,
            s_sc, v_sc, su, vu, aggs, aggv);
        edge_msg<<<dim3((NE+255)/256), blk, 0, stream>>>(
            snd, rcv, nhat, radial, su, vu,
            W1T+l*512, W2T+l*4096, W3+l*512, aggs, aggv);
        node_post<<<dim3((NN+255)/256), blk, 0, stream>>>(
            aggs, aggv, Wds+l*9, Wdv+l*10, s_sc, v_sc, s, v, out, (l==2)?1:0);
    }
}

// Round 4
// 3034.766 us; speedup vs baseline: 1.0038x; 1.0038x over previous
//
#include <hip/hip_runtime.h>
#include <math.h>

#define NN 50000
#define NE 1000000

constexpr float kC121    = 2.1213203435596424f;
constexpr float kSqrt3   = 1.7320508075688772f;
constexpr float kInvSqrt2= 0.7071067811865475f;
constexpr float kInvSqrt8= 0.35355339059327373f;
constexpr float kInvSqrt3= 0.5773502691896258f;
constexpr float kInvSqrt5= 0.4472135954999579f;
constexpr float kSqrt2   = 1.4142135623730951f;
constexpr float kPi      = 3.14159265358979323846f;

__device__ __forceinline__ float swishf(float x){
    return x / (1.0f + __expf(-x));
}

// Two DISTINCT repetition macros (the preprocessor will not re-expand a
// macro inside its own expansion — round-3 compile failure).
#define REP64A(M) M(0) M(1) M(2) M(3) M(4) M(5) M(6) M(7) M(8) M(9) \
 M(10) M(11) M(12) M(13) M(14) M(15) M(16) M(17) M(18) M(19) \
 M(20) M(21) M(22) M(23) M(24) M(25) M(26) M(27) M(28) M(29) \
 M(30) M(31) M(32) M(33) M(34) M(35) M(36) M(37) M(38) M(39) \
 M(40) M(41) M(42) M(43) M(44) M(45) M(46) M(47) M(48) M(49) \
 M(50) M(51) M(52) M(53) M(54) M(55) M(56) M(57) M(58) M(59) \
 M(60) M(61) M(62) M(63)
#define REP64B(M) M(0) M(1) M(2) M(3) M(4) M(5) M(6) M(7) M(8) M(9) \
 M(10) M(11) M(12) M(13) M(14) M(15) M(16) M(17) M(18) M(19) \
 M(20) M(21) M(22) M(23) M(24) M(25) M(26) M(27) M(28) M(29) \
 M(30) M(31) M(32) M(33) M(34) M(35) M(36) M(37) M(38) M(39) \
 M(40) M(41) M(42) M(43) M(44) M(45) M(46) M(47) M(48) M(49) \
 M(50) M(51) M(52) M(53) M(54) M(55) M(56) M(57) M(58) M(59) \
 M(60) M(61) M(62) M(63)

// Transpose W1 (3x8x64 -> 3x64x8) and W2 (3x64x64 -> 3x64x64^T) so the
// per-edge MLP reads contiguous rows at wave-uniform addresses (s_load).
__global__ void transpose_w(const float* __restrict__ W1, const float* __restrict__ W2,
                            float* __restrict__ W1T, float* __restrict__ W2T){
    int i = blockIdx.x*blockDim.x + threadIdx.x;
    if (i < 3*8*64){
        int l = i/512, r = i%512; int k = r/64, j = r%64;
        W1T[l*512 + j*8 + k] = W1[i];
    }
    if (i < 3*64*64){
        int l = i/4096, r = i%4096; int k = r/64, j = r%64;
        W2T[l*4096 + j*64 + k] = W2[i];
    }
}

__global__ void edge_geom(const float* __restrict__ pos,
                          const int* __restrict__ snd,
                          const int* __restrict__ rcv,
                          float* __restrict__ nhat,
                          float* __restrict__ radial){
    int e = blockIdx.x*blockDim.x + threadIdx.x;
    if (e >= NE) return;
    int s = snd[e], r = rcv[e];
    float vx = pos[r*3+0]-pos[s*3+0];
    float vy = pos[r*3+1]-pos[s*3+1];
    float vz = pos[r*3+2]-pos[s*3+2];
    float len = sqrtf(vx*vx+vy*vy+vz*vz);
    float safe = (len==0.f)?1.f:len;
    float inv = 1.f/safe;
    nhat[e*3+0]=vx*inv; nhat[e*3+1]=vy*inv; nhat[e*3+2]=vz*inv;
    float x = len;
    float x3=x*x*x, x6=x3*x3, x7=x6*x, x8=x7*x;
    float poly = 1.f - 28.f*x6 + 48.f*x7 - 21.f*x8;
    float env = (x<1.f)?poly:0.f;
    float c = kSqrt2*env*inv;
    // sin(k*pi*len) via recurrence: s_{k+1} = 2*cos(pi*len)*s_k - s_{k-1}
    float s1, c1;
    __sincosf(kPi*len, &s1, &c1);
    float tc = 2.f*c1;
    float sk_m1 = 0.f, sk = s1;
    float zero = (len==0.f)?0.f:1.f;
    #pragma unroll
    for (int k=1;k<=8;k++){
        radial[e*8+k-1] = sk*c*zero;
        float nxt = tc*sk - sk_m1;
        sk_m1 = sk; sk = nxt;
    }
}

__global__ void node_init(const float* __restrict__ nf,
                          float* __restrict__ s, float* __restrict__ v){
    int n = blockIdx.x*blockDim.x + threadIdx.x;
    if (n >= NN) return;
    s[n] = nf[n*7];
    #pragma unroll
    for (int i=0;i<6;i++) v[n*6+i] = nf[n*7+1+i];
}

__global__ void node_pre(const float* __restrict__ s, const float* __restrict__ v,
                         const float* __restrict__ Wss, const float* __restrict__ Wsv,
                         const float* __restrict__ Wus, const float* __restrict__ Wuv,
                         float* __restrict__ s_sc, float* __restrict__ v_sc,
                         float* __restrict__ su, float* __restrict__ vu,
                         float* __restrict__ aggs, float* __restrict__ aggv){
    int n = blockIdx.x*blockDim.x + threadIdx.x;
    if (n >= NN) return;
    float sv = s[n];
    float vv[6];
    #pragma unroll
    for (int i=0;i<6;i++) vv[i] = v[n*6+i];
    #pragma unroll
    for (int i=0;i<3;i++) s_sc[n*3+i] = sv*Wss[i];
    #pragma unroll
    for (int k=0;k<2;k++)
        #pragma unroll
        for (int c=0;c<3;c++)
            v_sc[n*6+k*3+c] = (vv[c]*Wsv[0*2+k] + vv[3+c]*Wsv[1*2+k]) * kInvSqrt2;
    su[n] = sv * Wus[0];
    #pragma unroll
    for (int k=0;k<2;k++)
        #pragma unroll
        for (int c=0;c<3;c++)
            vu[n*6+k*3+c] = (vv[c]*Wuv[0*2+k] + vv[3+c]*Wuv[1*2+k]) * kInvSqrt2;
    #pragma unroll
    for (int i=0;i<3;i++) aggs[n*3+i] = 0.f;
    #pragma unroll
    for (int i=0;i<15;i++) aggv[n*15+i] = 0.f;
}

__global__ void __launch_bounds__(256) edge_msg(
    const int* __restrict__ snd, const int* __restrict__ rcv,
    const float* __restrict__ nhat, const float* __restrict__ radial,
    const float* __restrict__ su, const float* __restrict__ vu,
    const float* __restrict__ W1T, const float* __restrict__ W2T,
    const float* __restrict__ W3,
    float* __restrict__ aggs, float* __restrict__ aggv){
    int e = blockIdx.x*blockDim.x + threadIdx.x;
    if (e >= NE) return;

    float r0 = radial[e*8+0], r1 = radial[e*8+1], r2 = radial[e*8+2], r3 = radial[e*8+3];
    float r4 = radial[e*8+4], r5 = radial[e*8+5], r6 = radial[e*8+6], r7 = radial[e*8+7];

    // stage 1: h_j = swish((rad . W1T_row_j) / sqrt8) — 64 NAMED scalars (no scratch)
#define STAGE1(J) float h_##J; { const float* w = W1T + (J)*8; \
    float a = fmaf(r0,w[0],fmaf(r1,w[1],fmaf(r2,w[2],fmaf(r3,w[3], \
              fmaf(r4,w[4],fmaf(r5,w[5],fmaf(r6,w[6],r7*w[7]))))))); \
    h_##J = swishf(a*kInvSqrt8); }
    REP64A(STAGE1)
#undef STAGE1

    // stage 2+3: stream over j; acc = h . W2T_row_j; mix += swish(acc/8) * W3_row_j
    float m0=0.f,m1=0.f,m2=0.f,m3=0.f,m4=0.f,m5=0.f,m6=0.f,m7=0.f;
#define ACCT(K) a = fmaf(h_##K, w[K], a);
#define STAGE2(J) { const float* w = W2T + (J)*64; float a = 0.f; REP64B(ACCT) \
    a = swishf(a*0.125f); const float* w3 = W3 + (J)*8; \
    m0=fmaf(a,w3[0],m0); m1=fmaf(a,w3[1],m1); m2=fmaf(a,w3[2],m2); m3=fmaf(a,w3[3],m3); \
    m4=fmaf(a,w3[4],m4); m5=fmaf(a,w3[5],m5); m6=fmaf(a,w3[6],m6); m7=fmaf(a,w3[7],m7); }
    REP64A(STAGE2)
#undef STAGE2
#undef ACCT
    m0*=0.125f; m1*=0.125f; m2*=0.125f; m3*=0.125f;
    m4*=0.125f; m5*=0.125f; m6*=0.125f; m7*=0.125f;

    int sn = snd[e], rn = rcv[e];
    float se = su[sn];
    float ve[6];
    #pragma unroll
    for (int i=0;i<6;i++) ve[i] = vu[sn*6+i];
    float nh[3];
    #pragma unroll
    for (int c=0;c<3;c++) nh[c] = nhat[e*3+c];
    float vd0 = ve[0]*nh[0]+ve[1]*nh[1]+ve[2]*nh[2];
    float vd1 = ve[3]*nh[0]+ve[4]*nh[1]+ve[5]*nh[2];

    atomicAdd(&aggs[rn*3+0], se *m0);
    atomicAdd(&aggs[rn*3+1], vd0*m1);
    atomicAdd(&aggs[rn*3+2], vd1*m2);

    #pragma unroll
    for (int c=0;c<3;c++){
        atomicAdd(&aggv[rn*15+0 +c], ve[c]*m3);
        atomicAdd(&aggv[rn*15+3 +c], ve[3+c]*m4);
        atomicAdd(&aggv[rn*15+6 +c], kC121*(vd0*nh[c]-ve[c]*(1.f/3.f))*m5);
        atomicAdd(&aggv[rn*15+9 +c], kC121*(vd1*nh[c]-ve[3+c]*(1.f/3.f))*m6);
        atomicAdd(&aggv[rn*15+12+c], kSqrt3*se*nh[c]*m7);
    }
}

__global__ void node_post(const float* __restrict__ aggs, const float* __restrict__ aggv,
                          const float* __restrict__ Wds, const float* __restrict__ Wdv,
                          const float* __restrict__ s_sc, const float* __restrict__ v_sc,
                          float* __restrict__ s, float* __restrict__ v,
                          float* __restrict__ out, int is_last){
    int n = blockIdx.x*blockDim.x + threadIdx.x;
    if (n >= NN) return;
    float as[3];
    #pragma unroll
    for (int j=0;j<3;j++) as[j] = aggs[n*3+j];
    float st[3];
    #pragma unroll
    for (int i=0;i<3;i++)
        st[i] = (as[0]*Wds[0*3+i]+as[1]*Wds[1*3+i]+as[2]*Wds[2*3+i])*kInvSqrt3 + s_sc[n*3+i];
    float vt[6];
    #pragma unroll
    for (int k=0;k<2;k++)
        #pragma unroll
        for (int c=0;c<3;c++){
            float acc = 0.f;
            #pragma unroll
            for (int m=0;m<5;m++) acc += aggv[n*15+m*3+c]*Wdv[m*2+k];
            vt[k*3+c] = acc*kInvSqrt5 + v_sc[n*6+k*3+c];
        }
    float snew = swishf(st[0]);
    float g1 = swishf(st[1]), g2 = swishf(st[2]);
    s[n] = snew;
    #pragma unroll
    for (int c=0;c<3;c++){
        float v0 = vt[c]*g1;
        float v1 = vt[3+c]*g2;
        v[n*6+c]   = v0;
        v[n*6+3+c] = v1;
        if (is_last) out[n*3+c] = v0;
    }
}

extern "C" void kernel_launch(void* const* d_in, const int* in_sizes, int n_in,
                              void* d_out, int out_size, void* d_ws, size_t ws_size,
                              hipStream_t stream){
    const float* pos = (const float*)d_in[0];
    const float* nf  = (const float*)d_in[1];
    const int*   snd = (const int*)d_in[2];
    const int*   rcv = (const int*)d_in[3];
    const float* Wss = (const float*)d_in[4];
    const float* Wsv = (const float*)d_in[5];
    const float* Wus = (const float*)d_in[6];
    const float* Wuv = (const float*)d_in[7];
    const float* W1  = (const float*)d_in[8];
    const float* W2  = (const float*)d_in[9];
    const float* W3  = (const float*)d_in[10];
    const float* Wds = (const float*)d_in[11];
    const float* Wdv = (const float*)d_in[12];
    float* out = (float*)d_out;

    float* p = (float*)d_ws;
    float* nhat   = p; p += (size_t)NE*3;
    float* radial = p; p += (size_t)NE*8;
    float* s      = p; p += NN;
    float* v      = p; p += NN*6;
    float* s_sc   = p; p += NN*3;
    float* v_sc   = p; p += NN*6;
    float* su     = p; p += NN;
    float* vu     = p; p += NN*6;
    float* aggs   = p; p += NN*3;
    float* aggv   = p; p += NN*15;
    float* W1T    = p; p += 3*512;
    float* W2T    = p; p += 3*4096;

    dim3 blk(256);
    transpose_w<<<dim3((3*4096+255)/256), blk, 0, stream>>>(W1, W2, W1T, W2T);
    edge_geom<<<dim3((NE+255)/256), blk, 0, stream>>>(pos, snd, rcv, nhat, radial);
    node_init<<<dim3((NN+255)/256), blk, 0, stream>>>(nf, s, v);
    for (int l=0;l<3;l++){
        node_pre<<<dim3((NN+255)/256), blk, 0, stream>>>(
            s, v, Wss+l*3, Wsv+l*4, Wus+l, Wuv+l*4,
            s_sc, v_sc, su, vu, aggs, aggv);
        edge_msg<<<dim3((NE+255)/256), blk, 0, stream>>>(
            snd, rcv, nhat, radial, su, vu,
            W1T+l*512, W2T+l*4096, W3+l*512, aggs, aggv);
        node_post<<<dim3((NN+255)/256), blk, 0, stream>>>(
            aggs, aggv, Wds+l*9, Wdv+l*10, s_sc, v_sc, s, v, out, (l==2)?1:0);
    }
}

// Round 5
// 1105.450 us; speedup vs baseline: 2.7557x; 2.7453x over previous
//
#include <hip/hip_runtime.h>
#include <math.h>

#define NN 50000
#define NE 1000000

constexpr float kC121    = 2.1213203435596424f;
constexpr float kSqrt3   = 1.7320508075688772f;
constexpr float kInvSqrt2= 0.7071067811865475f;
constexpr float kInvSqrt8= 0.35355339059327373f;
constexpr float kInvSqrt3= 0.5773502691896258f;
constexpr float kInvSqrt5= 0.4472135954999579f;
constexpr float kSqrt2   = 1.4142135623730951f;
constexpr float kPi      = 3.14159265358979323846f;

__device__ __forceinline__ float swishf(float x){
    return x / (1.0f + __expf(-x));
}

// Two DISTINCT repetition macros (preprocessor won't re-expand a macro
// inside its own expansion).
#define REP64A(M) M(0) M(1) M(2) M(3) M(4) M(5) M(6) M(7) M(8) M(9) \
 M(10) M(11) M(12) M(13) M(14) M(15) M(16) M(17) M(18) M(19) \
 M(20) M(21) M(22) M(23) M(24) M(25) M(26) M(27) M(28) M(29) \
 M(30) M(31) M(32) M(33) M(34) M(35) M(36) M(37) M(38) M(39) \
 M(40) M(41) M(42) M(43) M(44) M(45) M(46) M(47) M(48) M(49) \
 M(50) M(51) M(52) M(53) M(54) M(55) M(56) M(57) M(58) M(59) \
 M(60) M(61) M(62) M(63)
#define REP64B(M) M(0) M(1) M(2) M(3) M(4) M(5) M(6) M(7) M(8) M(9) \
 M(10) M(11) M(12) M(13) M(14) M(15) M(16) M(17) M(18) M(19) \
 M(20) M(21) M(22) M(23) M(24) M(25) M(26) M(27) M(28) M(29) \
 M(30) M(31) M(32) M(33) M(34) M(35) M(36) M(37) M(38) M(39) \
 M(40) M(41) M(42) M(43) M(44) M(45) M(46) M(47) M(48) M(49) \
 M(50) M(51) M(52) M(53) M(54) M(55) M(56) M(57) M(58) M(59) \
 M(60) M(61) M(62) M(63)

// ---- MLP core shared by both edge-message kernels ----------------------
// Defines m0..m7 from r0..r7 using W1T/W2T/W3 (wave-uniform rows).
#define MLP_BODY \
    float m0=0.f,m1=0.f,m2=0.f,m3=0.f,m4=0.f,m5=0.f,m6=0.f,m7=0.f; \
    { \
    /* stage 1: 64 named scalars */ \
    REP64A(STAGE1) \
    /* stage 2+3 */ \
    REP64A(STAGE2) \
    } \
    m0*=0.125f; m1*=0.125f; m2*=0.125f; m3*=0.125f; \
    m4*=0.125f; m5*=0.125f; m6*=0.125f; m7*=0.125f;

#define STAGE1(J) float h_##J; { const float* w = W1T + (J)*8; \
    float a = fmaf(r0,w[0],fmaf(r1,w[1],fmaf(r2,w[2],fmaf(r3,w[3], \
              fmaf(r4,w[4],fmaf(r5,w[5],fmaf(r6,w[6],r7*w[7]))))))); \
    h_##J = swishf(a*kInvSqrt8); }
#define ACCT(K) a = fmaf(h_##K, w[K], a);
#define STAGE2(J) { const float* w = W2T + (J)*64; float a = 0.f; REP64B(ACCT) \
    a = swishf(a*0.125f); const float* w3 = W3 + (J)*8; \
    m0=fmaf(a,w3[0],m0); m1=fmaf(a,w3[1],m1); m2=fmaf(a,w3[2],m2); m3=fmaf(a,w3[3],m3); \
    m4=fmaf(a,w3[4],m4); m5=fmaf(a,w3[5],m5); m6=fmaf(a,w3[6],m6); m7=fmaf(a,w3[7],m7); }

// ------------------------------------------------------------------------

__global__ void transpose_w(const float* __restrict__ W1, const float* __restrict__ W2,
                            float* __restrict__ W1T, float* __restrict__ W2T){
    int i = blockIdx.x*blockDim.x + threadIdx.x;
    if (i < 3*8*64){
        int l = i/512, r = i%512; int k = r/64, j = r%64;
        W1T[l*512 + j*8 + k] = W1[i];
    }
    if (i < 3*64*64){
        int l = i/4096, r = i%4096; int k = r/64, j = r%64;
        W2T[l*4096 + j*64 + k] = W2[i];
    }
}

// ---- CSR build (once per call; receivers are call-constant) ------------
__global__ void hist_rcv(const int* __restrict__ rcv, int* __restrict__ cnt){
    int e = blockIdx.x*blockDim.x + threadIdx.x;
    if (e < NE) atomicAdd(&cnt[rcv[e]], 1);
}

// one block of 1024 threads: exclusive scan cnt[0..NN) -> rowptr[0..NN],
// wcursor = rowptr[0..NN)
__global__ void exscan(const int* __restrict__ cnt, int* __restrict__ rowptr,
                       int* __restrict__ wcur){
    __shared__ int smem[1024];
    __shared__ int carry_s;
    int tid = threadIdx.x;
    if (tid==0) carry_s = 0;
    __syncthreads();
    for (int base=0; base<NN; base+=1024){
        int i = base + tid;
        int v = (i<NN)? cnt[i] : 0;
        smem[tid] = v; __syncthreads();
        for (int off=1; off<1024; off<<=1){
            int t = (tid>=off)? smem[tid-off] : 0;
            __syncthreads();
            smem[tid] += t;
            __syncthreads();
        }
        int carry = carry_s;
        if (i<NN){ int ex = carry + smem[tid] - v; rowptr[i]=ex; wcur[i]=ex; }
        __syncthreads();
        if (tid==0) carry_s = carry + smem[1023];
        __syncthreads();
    }
    if (tid==0) rowptr[NN] = carry_s;
}

__global__ void scatter_edges(const int* __restrict__ snd, const int* __restrict__ rcv,
                              int* __restrict__ wcur,
                              int* __restrict__ slot, int* __restrict__ snd_s){
    int e = blockIdx.x*blockDim.x + threadIdx.x;
    if (e >= NE) return;
    int pos = atomicAdd(&wcur[rcv[e]], 1);
    slot[e] = pos;
    snd_s[pos] = snd[e];
}

// edge geometry; optionally scatter-writes to sorted slot (slot!=nullptr)
__global__ void edge_geom(const float* __restrict__ pos,
                          const int* __restrict__ snd,
                          const int* __restrict__ rcv,
                          const int* __restrict__ slot,
                          float* __restrict__ nhat,
                          float* __restrict__ radial){
    int e = blockIdx.x*blockDim.x + threadIdx.x;
    if (e >= NE) return;
    int s = snd[e], r = rcv[e];
    float vx = pos[r*3+0]-pos[s*3+0];
    float vy = pos[r*3+1]-pos[s*3+1];
    float vz = pos[r*3+2]-pos[s*3+2];
    float len = sqrtf(vx*vx+vy*vy+vz*vz);
    float safe = (len==0.f)?1.f:len;
    float inv = 1.f/safe;
    int p = slot ? slot[e] : e;
    nhat[p*3+0]=vx*inv; nhat[p*3+1]=vy*inv; nhat[p*3+2]=vz*inv;
    float x = len;
    float x3=x*x*x, x6=x3*x3, x7=x6*x, x8=x7*x;
    float poly = 1.f - 28.f*x6 + 48.f*x7 - 21.f*x8;
    float env = (x<1.f)?poly:0.f;
    float c = kSqrt2*env*inv;
    float s1, c1;
    __sincosf(kPi*len, &s1, &c1);
    float tc = 2.f*c1;
    float sk_m1 = 0.f, sk = s1;
    float zero = (len==0.f)?0.f:1.f;
    #pragma unroll
    for (int k=1;k<=8;k++){
        radial[p*8+k-1] = sk*c*zero;
        float nxt = tc*sk - sk_m1;
        sk_m1 = sk; sk = nxt;
    }
}

__global__ void node_init(const float* __restrict__ nf,
                          float* __restrict__ s, float* __restrict__ v){
    int n = blockIdx.x*blockDim.x + threadIdx.x;
    if (n >= NN) return;
    s[n] = nf[n*7];
    #pragma unroll
    for (int i=0;i<6;i++) v[n*6+i] = nf[n*7+1+i];
}

__global__ void node_pre(const float* __restrict__ s, const float* __restrict__ v,
                         const float* __restrict__ Wss, const float* __restrict__ Wsv,
                         const float* __restrict__ Wus, const float* __restrict__ Wuv,
                         float* __restrict__ s_sc, float* __restrict__ v_sc,
                         float* __restrict__ su, float* __restrict__ vu){
    int n = blockIdx.x*blockDim.x + threadIdx.x;
    if (n >= NN) return;
    float sv = s[n];
    float vv[6];
    #pragma unroll
    for (int i=0;i<6;i++) vv[i] = v[n*6+i];
    #pragma unroll
    for (int i=0;i<3;i++) s_sc[n*3+i] = sv*Wss[i];
    #pragma unroll
    for (int k=0;k<2;k++)
        #pragma unroll
        for (int c=0;c<3;c++)
            v_sc[n*6+k*3+c] = (vv[c]*Wsv[0*2+k] + vv[3+c]*Wsv[1*2+k]) * kInvSqrt2;
    su[n] = sv * Wus[0];
    #pragma unroll
    for (int k=0;k<2;k++)
        #pragma unroll
        for (int c=0;c<3;c++)
            vu[n*6+k*3+c] = (vv[c]*Wuv[0*2+k] + vv[3+c]*Wuv[1*2+k]) * kInvSqrt2;
}

// ---- sorted path: per-edge message -> plain stores (no atomics) --------
__global__ void __launch_bounds__(256) edge_msg2(
    const int* __restrict__ snd_s,
    const float* __restrict__ nhat, const float* __restrict__ radial,
    const float* __restrict__ su, const float* __restrict__ vu,
    const float* __restrict__ W1T, const float* __restrict__ W2T,
    const float* __restrict__ W3,
    float* __restrict__ msg){
    int sidx = blockIdx.x*blockDim.x + threadIdx.x;
    if (sidx >= NE) return;

    float r0 = radial[sidx*8+0], r1 = radial[sidx*8+1], r2 = radial[sidx*8+2], r3 = radial[sidx*8+3];
    float r4 = radial[sidx*8+4], r5 = radial[sidx*8+5], r6 = radial[sidx*8+6], r7 = radial[sidx*8+7];

    MLP_BODY

    int sn = snd_s[sidx];
    float se = su[sn];
    float ve[6];
    #pragma unroll
    for (int i=0;i<6;i++) ve[i] = vu[sn*6+i];
    float nh[3];
    #pragma unroll
    for (int c=0;c<3;c++) nh[c] = nhat[sidx*3+c];
    float vd0 = ve[0]*nh[0]+ve[1]*nh[1]+ve[2]*nh[2];
    float vd1 = ve[3]*nh[0]+ve[4]*nh[1]+ve[5]*nh[2];

    float* mp = msg + (size_t)sidx*18;
    mp[0] = se *m0;
    mp[1] = vd0*m1;
    mp[2] = vd1*m2;
    #pragma unroll
    for (int c=0;c<3;c++){
        mp[3 +c] = ve[c]*m3;
        mp[6 +c] = ve[3+c]*m4;
        mp[9 +c] = kC121*(vd0*nh[c]-ve[c]*(1.f/3.f))*m5;
        mp[12+c] = kC121*(vd1*nh[c]-ve[3+c]*(1.f/3.f))*m6;
        mp[15+c] = kSqrt3*se*nh[c]*m7;
    }
}

// one thread per (node, col): sum the CSR row
__global__ void agg18(const float* __restrict__ msg, const int* __restrict__ rowptr,
                      float* __restrict__ agg){
    int t = blockIdx.x*blockDim.x + threadIdx.x;
    if (t >= NN*18) return;
    int n = t/18, c = t%18;
    int b = rowptr[n], e = rowptr[n+1];
    float acc = 0.f;
    for (int s=b; s<e; ++s) acc += msg[(size_t)s*18+c];
    agg[t] = acc;
}

__global__ void node_post18(const float* __restrict__ agg,
                            const float* __restrict__ Wds, const float* __restrict__ Wdv,
                            const float* __restrict__ s_sc, const float* __restrict__ v_sc,
                            float* __restrict__ s, float* __restrict__ v,
                            float* __restrict__ out, int is_last){
    int n = blockIdx.x*blockDim.x + threadIdx.x;
    if (n >= NN) return;
    const float* a = agg + n*18;
    float st[3];
    #pragma unroll
    for (int i=0;i<3;i++)
        st[i] = (a[0]*Wds[0*3+i]+a[1]*Wds[1*3+i]+a[2]*Wds[2*3+i])*kInvSqrt3 + s_sc[n*3+i];
    float vt[6];
    #pragma unroll
    for (int k=0;k<2;k++)
        #pragma unroll
        for (int c=0;c<3;c++){
            float acc = 0.f;
            #pragma unroll
            for (int m=0;m<5;m++) acc += a[3+m*3+c]*Wdv[m*2+k];
            vt[k*3+c] = acc*kInvSqrt5 + v_sc[n*6+k*3+c];
        }
    float snew = swishf(st[0]);
    float g1 = swishf(st[1]), g2 = swishf(st[2]);
    s[n] = snew;
    #pragma unroll
    for (int c=0;c<3;c++){
        float v0 = vt[c]*g1;
        float v1 = vt[3+c]*g2;
        v[n*6+c]   = v0;
        v[n*6+3+c] = v1;
        if (is_last) out[n*3+c] = v0;
    }
}

// ---- fallback path (atomics), proven correct in round 4 ---------------
__global__ void __launch_bounds__(256) edge_msg_atomic(
    const int* __restrict__ snd, const int* __restrict__ rcv,
    const float* __restrict__ nhat, const float* __restrict__ radial,
    const float* __restrict__ su, const float* __restrict__ vu,
    const float* __restrict__ W1T, const float* __restrict__ W2T,
    const float* __restrict__ W3,
    float* __restrict__ aggs, float* __restrict__ aggv){
    int e = blockIdx.x*blockDim.x + threadIdx.x;
    if (e >= NE) return;

    float r0 = radial[e*8+0], r1 = radial[e*8+1], r2 = radial[e*8+2], r3 = radial[e*8+3];
    float r4 = radial[e*8+4], r5 = radial[e*8+5], r6 = radial[e*8+6], r7 = radial[e*8+7];

    MLP_BODY

    int sn = snd[e], rn = rcv[e];
    float se = su[sn];
    float ve[6];
    #pragma unroll
    for (int i=0;i<6;i++) ve[i] = vu[sn*6+i];
    float nh[3];
    #pragma unroll
    for (int c=0;c<3;c++) nh[c] = nhat[e*3+c];
    float vd0 = ve[0]*nh[0]+ve[1]*nh[1]+ve[2]*nh[2];
    float vd1 = ve[3]*nh[0]+ve[4]*nh[1]+ve[5]*nh[2];

    atomicAdd(&aggs[rn*3+0], se *m0);
    atomicAdd(&aggs[rn*3+1], vd0*m1);
    atomicAdd(&aggs[rn*3+2], vd1*m2);
    #pragma unroll
    for (int c=0;c<3;c++){
        atomicAdd(&aggv[rn*15+0 +c], ve[c]*m3);
        atomicAdd(&aggv[rn*15+3 +c], ve[3+c]*m4);
        atomicAdd(&aggv[rn*15+6 +c], kC121*(vd0*nh[c]-ve[c]*(1.f/3.f))*m5);
        atomicAdd(&aggv[rn*15+9 +c], kC121*(vd1*nh[c]-ve[3+c]*(1.f/3.f))*m6);
        atomicAdd(&aggv[rn*15+12+c], kSqrt3*se*nh[c]*m7);
    }
}

__global__ void node_post_split(const float* __restrict__ aggs, const float* __restrict__ aggv,
                                const float* __restrict__ Wds, const float* __restrict__ Wdv,
                                const float* __restrict__ s_sc, const float* __restrict__ v_sc,
                                float* __restrict__ s, float* __restrict__ v,
                                float* __restrict__ out, int is_last){
    int n = blockIdx.x*blockDim.x + threadIdx.x;
    if (n >= NN) return;
    float as[3];
    #pragma unroll
    for (int j=0;j<3;j++) as[j] = aggs[n*3+j];
    float st[3];
    #pragma unroll
    for (int i=0;i<3;i++)
        st[i] = (as[0]*Wds[0*3+i]+as[1]*Wds[1*3+i]+as[2]*Wds[2*3+i])*kInvSqrt3 + s_sc[n*3+i];
    float vt[6];
    #pragma unroll
    for (int k=0;k<2;k++)
        #pragma unroll
        for (int c=0;c<3;c++){
            float acc = 0.f;
            #pragma unroll
            for (int m=0;m<5;m++) acc += aggv[n*15+m*3+c]*Wdv[m*2+k];
            vt[k*3+c] = acc*kInvSqrt5 + v_sc[n*6+k*3+c];
        }
    float snew = swishf(st[0]);
    float g1 = swishf(st[1]), g2 = swishf(st[2]);
    s[n] = snew;
    #pragma unroll
    for (int c=0;c<3;c++){
        float v0 = vt[c]*g1;
        float v1 = vt[3+c]*g2;
        v[n*6+c]   = v0;
        v[n*6+3+c] = v1;
        if (is_last) out[n*3+c] = v0;
    }
}

extern "C" void kernel_launch(void* const* d_in, const int* in_sizes, int n_in,
                              void* d_out, int out_size, void* d_ws, size_t ws_size,
                              hipStream_t stream){
    const float* pos = (const float*)d_in[0];
    const float* nf  = (const float*)d_in[1];
    const int*   snd = (const int*)d_in[2];
    const int*   rcv = (const int*)d_in[3];
    const float* Wss = (const float*)d_in[4];
    const float* Wsv = (const float*)d_in[5];
    const float* Wus = (const float*)d_in[6];
    const float* Wuv = (const float*)d_in[7];
    const float* W1  = (const float*)d_in[8];
    const float* W2  = (const float*)d_in[9];
    const float* W3  = (const float*)d_in[10];
    const float* Wds = (const float*)d_in[11];
    const float* Wdv = (const float*)d_in[12];
    float* out = (float*)d_out;

    dim3 blk(256);
    dim3 gE((NE+255)/256), gN((NN+255)/256);

    // sorted-path workspace need: ~133 MB
    size_t need_sorted = ((size_t)NE*(3+8+18) + (size_t)NN*(1+6+3+6+1+6+18) + 1536 + 12288)*4
                       + ((size_t)NN*3 + 1 + (size_t)NE*2)*4;

    if (ws_size >= need_sorted){
        float* p = (float*)d_ws;
        float* nhat_s  = p; p += (size_t)NE*3;
        float* radial_s= p; p += (size_t)NE*8;
        float* msg     = p; p += (size_t)NE*18;
        float* s       = p; p += NN;
        float* v       = p; p += NN*6;
        float* s_sc    = p; p += NN*3;
        float* v_sc    = p; p += NN*6;
        float* su      = p; p += NN;
        float* vu      = p; p += NN*6;
        float* agg     = p; p += NN*18;
        float* W1T     = p; p += 1536;
        float* W2T     = p; p += 12288;
        int* ip = (int*)p;
        int* cnt    = ip; ip += NN;
        int* rowptr = ip; ip += NN+1;
        int* wcur   = ip; ip += NN;
        int* slot   = ip; ip += NE;
        int* snd_s  = ip; ip += NE;

        transpose_w<<<dim3((3*4096+255)/256), blk, 0, stream>>>(W1, W2, W1T, W2T);
        hipMemsetAsync(cnt, 0, NN*sizeof(int), stream);
        hist_rcv<<<gE, blk, 0, stream>>>(rcv, cnt);
        exscan<<<dim3(1), dim3(1024), 0, stream>>>(cnt, rowptr, wcur);
        scatter_edges<<<gE, blk, 0, stream>>>(snd, rcv, wcur, slot, snd_s);
        edge_geom<<<gE, blk, 0, stream>>>(pos, snd, rcv, slot, nhat_s, radial_s);
        node_init<<<gN, blk, 0, stream>>>(nf, s, v);
        for (int l=0;l<3;l++){
            node_pre<<<gN, blk, 0, stream>>>(
                s, v, Wss+l*3, Wsv+l*4, Wus+l, Wuv+l*4, s_sc, v_sc, su, vu);
            edge_msg2<<<gE, blk, 0, stream>>>(
                snd_s, nhat_s, radial_s, su, vu,
                W1T+l*512, W2T+l*4096, W3+l*512, msg);
            agg18<<<dim3((NN*18+255)/256), blk, 0, stream>>>(msg, rowptr, agg);
            node_post18<<<gN, blk, 0, stream>>>(
                agg, Wds+l*9, Wdv+l*10, s_sc, v_sc, s, v, out, (l==2)?1:0);
        }
    } else {
        // fallback: proven atomic path
        float* p = (float*)d_ws;
        float* nhat   = p; p += (size_t)NE*3;
        float* radial = p; p += (size_t)NE*8;
        float* s      = p; p += NN;
        float* v      = p; p += NN*6;
        float* s_sc   = p; p += NN*3;
        float* v_sc   = p; p += NN*6;
        float* su     = p; p += NN;
        float* vu     = p; p += NN*6;
        float* aggs   = p; p += NN*3;
        float* aggv   = p; p += NN*15;
        float* W1T    = p; p += 1536;
        float* W2T    = p; p += 12288;

        transpose_w<<<dim3((3*4096+255)/256), blk, 0, stream>>>(W1, W2, W1T, W2T);
        edge_geom<<<gE, blk, 0, stream>>>(pos, snd, rcv, nullptr, nhat, radial);
        node_init<<<gN, blk, 0, stream>>>(nf, s, v);
        for (int l=0;l<3;l++){
            node_pre<<<gN, blk, 0, stream>>>(
                s, v, Wss+l*3, Wsv+l*4, Wus+l, Wuv+l*4, s_sc, v_sc, su, vu);
            hipMemsetAsync(aggs, 0, NN*3*sizeof(float), stream);
            hipMemsetAsync(aggv, 0, NN*15*sizeof(float), stream);
            edge_msg_atomic<<<gE, blk, 0, stream>>>(
                snd, rcv, nhat, radial, su, vu,
                W1T+l*512, W2T+l*4096, W3+l*512, aggs, aggv);
            node_post_split<<<gN, blk, 0, stream>>>(
                aggs, aggv, Wds+l*9, Wdv+l*10, s_sc, v_sc, s, v, out, (l==2)?1:0);
        }
    }
}

// Round 6
// 1034.483 us; speedup vs baseline: 2.9447x; 1.0686x over previous
//
#include <hip/hip_runtime.h>
#include <math.h>

#define NN 50000
#define NE 1000000

constexpr float kC121    = 2.1213203435596424f;
constexpr float kSqrt3   = 1.7320508075688772f;
constexpr float kInvSqrt2= 0.7071067811865475f;
constexpr float kInvSqrt8= 0.35355339059327373f;
constexpr float kInvSqrt3= 0.5773502691896258f;
constexpr float kInvSqrt5= 0.4472135954999579f;
constexpr float kSqrt2   = 1.4142135623730951f;
constexpr float kPi      = 3.14159265358979323846f;

__device__ __forceinline__ float swishf(float x){
    return x / (1.0f + __expf(-x));
}

// Two DISTINCT repetition macros (preprocessor won't re-expand a macro
// inside its own expansion).
#define REP64A(M) M(0) M(1) M(2) M(3) M(4) M(5) M(6) M(7) M(8) M(9) \
 M(10) M(11) M(12) M(13) M(14) M(15) M(16) M(17) M(18) M(19) \
 M(20) M(21) M(22) M(23) M(24) M(25) M(26) M(27) M(28) M(29) \
 M(30) M(31) M(32) M(33) M(34) M(35) M(36) M(37) M(38) M(39) \
 M(40) M(41) M(42) M(43) M(44) M(45) M(46) M(47) M(48) M(49) \
 M(50) M(51) M(52) M(53) M(54) M(55) M(56) M(57) M(58) M(59) \
 M(60) M(61) M(62) M(63)
#define REP64B(M) M(0) M(1) M(2) M(3) M(4) M(5) M(6) M(7) M(8) M(9) \
 M(10) M(11) M(12) M(13) M(14) M(15) M(16) M(17) M(18) M(19) \
 M(20) M(21) M(22) M(23) M(24) M(25) M(26) M(27) M(28) M(29) \
 M(30) M(31) M(32) M(33) M(34) M(35) M(36) M(37) M(38) M(39) \
 M(40) M(41) M(42) M(43) M(44) M(45) M(46) M(47) M(48) M(49) \
 M(50) M(51) M(52) M(53) M(54) M(55) M(56) M(57) M(58) M(59) \
 M(60) M(61) M(62) M(63)

// ---- MLP core shared by both edge-message kernels ----------------------
#define MLP_BODY \
    float m0=0.f,m1=0.f,m2=0.f,m3=0.f,m4=0.f,m5=0.f,m6=0.f,m7=0.f; \
    { \
    REP64A(STAGE1) \
    REP64A(STAGE2) \
    } \
    m0*=0.125f; m1*=0.125f; m2*=0.125f; m3*=0.125f; \
    m4*=0.125f; m5*=0.125f; m6*=0.125f; m7*=0.125f;

#define STAGE1(J) float h_##J; { const float* w = W1T + (J)*8; \
    float a = fmaf(r0,w[0],fmaf(r1,w[1],fmaf(r2,w[2],fmaf(r3,w[3], \
              fmaf(r4,w[4],fmaf(r5,w[5],fmaf(r6,w[6],r7*w[7]))))))); \
    h_##J = swishf(a*kInvSqrt8); }
#define ACCT(K) a = fmaf(h_##K, w[K], a);
#define STAGE2(J) { const float* w = W2T + (J)*64; float a = 0.f; REP64B(ACCT) \
    a = swishf(a*0.125f); const float* w3 = W3 + (J)*8; \
    m0=fmaf(a,w3[0],m0); m1=fmaf(a,w3[1],m1); m2=fmaf(a,w3[2],m2); m3=fmaf(a,w3[3],m3); \
    m4=fmaf(a,w3[4],m4); m5=fmaf(a,w3[5],m5); m6=fmaf(a,w3[6],m6); m7=fmaf(a,w3[7],m7); }

// ------------------------------------------------------------------------

__global__ void transpose_w(const float* __restrict__ W1, const float* __restrict__ W2,
                            float* __restrict__ W1T, float* __restrict__ W2T){
    int i = blockIdx.x*blockDim.x + threadIdx.x;
    if (i < 3*8*64){
        int l = i/512, r = i%512; int k = r/64, j = r%64;
        W1T[l*512 + j*8 + k] = W1[i];
    }
    if (i < 3*64*64){
        int l = i/4096, r = i%4096; int k = r/64, j = r%64;
        W2T[l*4096 + j*64 + k] = W2[i];
    }
}

// ---- CSR build (once per call; receivers are call-constant) ------------
__global__ void hist_rcv(const int* __restrict__ rcv, int* __restrict__ cnt){
    int e = blockIdx.x*blockDim.x + threadIdx.x;
    if (e < NE) atomicAdd(&cnt[rcv[e]], 1);
}

// one block of 1024 threads (16 waves): exclusive scan via wave shuffles,
// 4 elements/thread -> 13 outer iterations (was 49 barrier-heavy rounds).
__global__ void exscan(const int* __restrict__ cnt, int* __restrict__ rowptr,
                       int* __restrict__ wcur){
    __shared__ int wsum[16];
    __shared__ int carry_s;
    int tid = threadIdx.x;
    int lane = tid & 63, wv = tid >> 6;
    if (tid==0) carry_s = 0;
    __syncthreads();
    for (int base=0; base<NN; base+=4096){
        int i0 = base + tid*4;
        int v0 = (i0+0<NN)?cnt[i0+0]:0;
        int v1 = (i0+1<NN)?cnt[i0+1]:0;
        int v2 = (i0+2<NN)?cnt[i0+2]:0;
        int v3 = (i0+3<NN)?cnt[i0+3]:0;
        int t = v0+v1+v2+v3;
        // inclusive wave scan of t
        int sc = t;
        #pragma unroll
        for (int off=1; off<64; off<<=1){
            int u = __shfl_up(sc, off, 64);
            if (lane >= off) sc += u;
        }
        if (lane==63) wsum[wv] = sc;
        __syncthreads();
        if (wv==0 && lane<16){
            int ws = wsum[lane];
            #pragma unroll
            for (int off=1; off<16; off<<=1){
                int u = __shfl_up(ws, off, 64);
                if (lane>=off) ws += u;
            }
            wsum[lane] = ws;   // inclusive over waves
        }
        __syncthreads();
        int carry = carry_s;
        int wbase = (wv==0)?0:wsum[wv-1];
        int ex = carry + wbase + (sc - t);
        if (i0+0<NN){ rowptr[i0+0]=ex; wcur[i0+0]=ex; } ex += v0;
        if (i0+1<NN){ rowptr[i0+1]=ex; wcur[i0+1]=ex; } ex += v1;
        if (i0+2<NN){ rowptr[i0+2]=ex; wcur[i0+2]=ex; } ex += v2;
        if (i0+3<NN){ rowptr[i0+3]=ex; wcur[i0+3]=ex; }
        __syncthreads();
        if (tid==0) carry_s = carry + wsum[15];
        __syncthreads();
    }
    if (threadIdx.x==0) rowptr[NN] = carry_s;
}

__global__ void scatter_edges(const int* __restrict__ snd, const int* __restrict__ rcv,
                              int* __restrict__ wcur,
                              int* __restrict__ slot, int* __restrict__ snd_s){
    int e = blockIdx.x*blockDim.x + threadIdx.x;
    if (e >= NE) return;
    int pos = atomicAdd(&wcur[rcv[e]], 1);
    slot[e] = pos;
    snd_s[pos] = snd[e];
}

__global__ void edge_geom(const float* __restrict__ pos,
                          const int* __restrict__ snd,
                          const int* __restrict__ rcv,
                          const int* __restrict__ slot,
                          float* __restrict__ nhat,
                          float* __restrict__ radial){
    int e = blockIdx.x*blockDim.x + threadIdx.x;
    if (e >= NE) return;
    int s = snd[e], r = rcv[e];
    float vx = pos[r*3+0]-pos[s*3+0];
    float vy = pos[r*3+1]-pos[s*3+1];
    float vz = pos[r*3+2]-pos[s*3+2];
    float len = sqrtf(vx*vx+vy*vy+vz*vz);
    float safe = (len==0.f)?1.f:len;
    float inv = 1.f/safe;
    int p = slot ? slot[e] : e;
    nhat[p*3+0]=vx*inv; nhat[p*3+1]=vy*inv; nhat[p*3+2]=vz*inv;
    float x = len;
    float x3=x*x*x, x6=x3*x3, x7=x6*x, x8=x7*x;
    float poly = 1.f - 28.f*x6 + 48.f*x7 - 21.f*x8;
    float env = (x<1.f)?poly:0.f;
    float c = kSqrt2*env*inv;
    float s1, c1;
    __sincosf(kPi*len, &s1, &c1);
    float tc = 2.f*c1;
    float sk_m1 = 0.f, sk = s1;
    float zero = (len==0.f)?0.f:1.f;
    #pragma unroll
    for (int k=1;k<=8;k++){
        radial[p*8+k-1] = sk*c*zero;
        float nxt = tc*sk - sk_m1;
        sk_m1 = sk; sk = nxt;
    }
}

__global__ void node_init(const float* __restrict__ nf,
                          float* __restrict__ s, float* __restrict__ v){
    int n = blockIdx.x*blockDim.x + threadIdx.x;
    if (n >= NN) return;
    s[n] = nf[n*7];
    #pragma unroll
    for (int i=0;i<6;i++) v[n*6+i] = nf[n*7+1+i];
}

__global__ void node_pre(const float* __restrict__ s, const float* __restrict__ v,
                         const float* __restrict__ Wss, const float* __restrict__ Wsv,
                         const float* __restrict__ Wus, const float* __restrict__ Wuv,
                         float* __restrict__ s_sc, float* __restrict__ v_sc,
                         float* __restrict__ su, float* __restrict__ vu){
    int n = blockIdx.x*blockDim.x + threadIdx.x;
    if (n >= NN) return;
    float sv = s[n];
    float vv[6];
    #pragma unroll
    for (int i=0;i<6;i++) vv[i] = v[n*6+i];
    #pragma unroll
    for (int i=0;i<3;i++) s_sc[n*3+i] = sv*Wss[i];
    #pragma unroll
    for (int k=0;k<2;k++)
        #pragma unroll
        for (int c=0;c<3;c++)
            v_sc[n*6+k*3+c] = (vv[c]*Wsv[0*2+k] + vv[3+c]*Wsv[1*2+k]) * kInvSqrt2;
    su[n] = sv * Wus[0];
    #pragma unroll
    for (int k=0;k<2;k++)
        #pragma unroll
        for (int c=0;c<3;c++)
            vu[n*6+k*3+c] = (vv[c]*Wuv[0*2+k] + vv[3+c]*Wuv[1*2+k]) * kInvSqrt2;
}

// ---- sorted path: per-edge message -> plain stores (no atomics) --------
// __launch_bounds__(256, 4): cap 128 VGPR so h_0..h_63 live in arch VGPRs
// (round-5: default heuristic chose 56 VGPR + AGPR shuffling -> 2.3x VALU
// instruction inflation via v_accvgpr_read/write per h access).
__global__ void __launch_bounds__(256, 4) edge_msg2(
    const int* __restrict__ snd_s,
    const float* __restrict__ nhat, const float* __restrict__ radial,
    const float* __restrict__ su, const float* __restrict__ vu,
    const float* __restrict__ W1T, const float* __restrict__ W2T,
    const float* __restrict__ W3,
    float* __restrict__ msg){
    int sidx = blockIdx.x*blockDim.x + threadIdx.x;
    if (sidx >= NE) return;

    float r0 = radial[sidx*8+0], r1 = radial[sidx*8+1], r2 = radial[sidx*8+2], r3 = radial[sidx*8+3];
    float r4 = radial[sidx*8+4], r5 = radial[sidx*8+5], r6 = radial[sidx*8+6], r7 = radial[sidx*8+7];

    MLP_BODY

    int sn = snd_s[sidx];
    float se = su[sn];
    float ve[6];
    #pragma unroll
    for (int i=0;i<6;i++) ve[i] = vu[sn*6+i];
    float nh[3];
    #pragma unroll
    for (int c=0;c<3;c++) nh[c] = nhat[sidx*3+c];
    float vd0 = ve[0]*nh[0]+ve[1]*nh[1]+ve[2]*nh[2];
    float vd1 = ve[3]*nh[0]+ve[4]*nh[1]+ve[5]*nh[2];

    float* mp = msg + (size_t)sidx*18;
    mp[0] = se *m0;
    mp[1] = vd0*m1;
    mp[2] = vd1*m2;
    #pragma unroll
    for (int c=0;c<3;c++){
        mp[3 +c] = ve[c]*m3;
        mp[6 +c] = ve[3+c]*m4;
        mp[9 +c] = kC121*(vd0*nh[c]-ve[c]*(1.f/3.f))*m5;
        mp[12+c] = kC121*(vd1*nh[c]-ve[3+c]*(1.f/3.f))*m6;
        mp[15+c] = kSqrt3*se*nh[c]*m7;
    }
}

// one thread per (node, col): sum the CSR row
__global__ void agg18(const float* __restrict__ msg, const int* __restrict__ rowptr,
                      float* __restrict__ agg){
    int t = blockIdx.x*blockDim.x + threadIdx.x;
    if (t >= NN*18) return;
    int n = t/18, c = t%18;
    int b = rowptr[n], e = rowptr[n+1];
    float acc = 0.f;
    for (int s=b; s<e; ++s) acc += msg[(size_t)s*18+c];
    agg[t] = acc;
}

__global__ void node_post18(const float* __restrict__ agg,
                            const float* __restrict__ Wds, const float* __restrict__ Wdv,
                            const float* __restrict__ s_sc, const float* __restrict__ v_sc,
                            float* __restrict__ s, float* __restrict__ v,
                            float* __restrict__ out, int is_last){
    int n = blockIdx.x*blockDim.x + threadIdx.x;
    if (n >= NN) return;
    const float* a = agg + n*18;
    float st[3];
    #pragma unroll
    for (int i=0;i<3;i++)
        st[i] = (a[0]*Wds[0*3+i]+a[1]*Wds[1*3+i]+a[2]*Wds[2*3+i])*kInvSqrt3 + s_sc[n*3+i];
    float vt[6];
    #pragma unroll
    for (int k=0;k<2;k++)
        #pragma unroll
        for (int c=0;c<3;c++){
            float acc = 0.f;
            #pragma unroll
            for (int m=0;m<5;m++) acc += a[3+m*3+c]*Wdv[m*2+k];
            vt[k*3+c] = acc*kInvSqrt5 + v_sc[n*6+k*3+c];
        }
    float snew = swishf(st[0]);
    float g1 = swishf(st[1]), g2 = swishf(st[2]);
    s[n] = snew;
    #pragma unroll
    for (int c=0;c<3;c++){
        float v0 = vt[c]*g1;
        float v1 = vt[3+c]*g2;
        v[n*6+c]   = v0;
        v[n*6+3+c] = v1;
        if (is_last) out[n*3+c] = v0;
    }
}

// ---- fallback path (atomics), proven correct in round 4 ---------------
__global__ void __launch_bounds__(256, 4) edge_msg_atomic(
    const int* __restrict__ snd, const int* __restrict__ rcv,
    const float* __restrict__ nhat, const float* __restrict__ radial,
    const float* __restrict__ su, const float* __restrict__ vu,
    const float* __restrict__ W1T, const float* __restrict__ W2T,
    const float* __restrict__ W3,
    float* __restrict__ aggs, float* __restrict__ aggv){
    int e = blockIdx.x*blockDim.x + threadIdx.x;
    if (e >= NE) return;

    float r0 = radial[e*8+0], r1 = radial[e*8+1], r2 = radial[e*8+2], r3 = radial[e*8+3];
    float r4 = radial[e*8+4], r5 = radial[e*8+5], r6 = radial[e*8+6], r7 = radial[e*8+7];

    MLP_BODY

    int sn = snd[e], rn = rcv[e];
    float se = su[sn];
    float ve[6];
    #pragma unroll
    for (int i=0;i<6;i++) ve[i] = vu[sn*6+i];
    float nh[3];
    #pragma unroll
    for (int c=0;c<3;c++) nh[c] = nhat[e*3+c];
    float vd0 = ve[0]*nh[0]+ve[1]*nh[1]+ve[2]*nh[2];
    float vd1 = ve[3]*nh[0]+ve[4]*nh[1]+ve[5]*nh[2];

    atomicAdd(&aggs[rn*3+0], se *m0);
    atomicAdd(&aggs[rn*3+1], vd0*m1);
    atomicAdd(&aggs[rn*3+2], vd1*m2);
    #pragma unroll
    for (int c=0;c<3;c++){
        atomicAdd(&aggv[rn*15+0 +c], ve[c]*m3);
        atomicAdd(&aggv[rn*15+3 +c], ve[3+c]*m4);
        atomicAdd(&aggv[rn*15+6 +c], kC121*(vd0*nh[c]-ve[c]*(1.f/3.f))*m5);
        atomicAdd(&aggv[rn*15+9 +c], kC121*(vd1*nh[c]-ve[3+c]*(1.f/3.f))*m6);
        atomicAdd(&aggv[rn*15+12+c], kSqrt3*se*nh[c]*m7);
    }
}

__global__ void node_post_split(const float* __restrict__ aggs, const float* __restrict__ aggv,
                                const float* __restrict__ Wds, const float* __restrict__ Wdv,
                                const float* __restrict__ s_sc, const float* __restrict__ v_sc,
                                float* __restrict__ s, float* __restrict__ v,
                                float* __restrict__ out, int is_last){
    int n = blockIdx.x*blockDim.x + threadIdx.x;
    if (n >= NN) return;
    float as[3];
    #pragma unroll
    for (int j=0;j<3;j++) as[j] = aggs[n*3+j];
    float st[3];
    #pragma unroll
    for (int i=0;i<3;i++)
        st[i] = (as[0]*Wds[0*3+i]+as[1]*Wds[1*3+i]+as[2]*Wds[2*3+i])*kInvSqrt3 + s_sc[n*3+i];
    float vt[6];
    #pragma unroll
    for (int k=0;k<2;k++)
        #pragma unroll
        for (int c=0;c<3;c++){
            float acc = 0.f;
            #pragma unroll
            for (int m=0;m<5;m++) acc += aggv[n*15+m*3+c]*Wdv[m*2+k];
            vt[k*3+c] = acc*kInvSqrt5 + v_sc[n*6+k*3+c];
        }
    float snew = swishf(st[0]);
    float g1 = swishf(st[1]), g2 = swishf(st[2]);
    s[n] = snew;
    #pragma unroll
    for (int c=0;c<3;c++){
        float v0 = vt[c]*g1;
        float v1 = vt[3+c]*g2;
        v[n*6+c]   = v0;
        v[n*6+3+c] = v1;
        if (is_last) out[n*3+c] = v0;
    }
}

extern "C" void kernel_launch(void* const* d_in, const int* in_sizes, int n_in,
                              void* d_out, int out_size, void* d_ws, size_t ws_size,
                              hipStream_t stream){
    const float* pos = (const float*)d_in[0];
    const float* nf  = (const float*)d_in[1];
    const int*   snd = (const int*)d_in[2];
    const int*   rcv = (const int*)d_in[3];
    const float* Wss = (const float*)d_in[4];
    const float* Wsv = (const float*)d_in[5];
    const float* Wus = (const float*)d_in[6];
    const float* Wuv = (const float*)d_in[7];
    const float* W1  = (const float*)d_in[8];
    const float* W2  = (const float*)d_in[9];
    const float* W3  = (const float*)d_in[10];
    const float* Wds = (const float*)d_in[11];
    const float* Wdv = (const float*)d_in[12];
    float* out = (float*)d_out;

    dim3 blk(256);
    dim3 gE((NE+255)/256), gN((NN+255)/256);

    size_t need_sorted = ((size_t)NE*(3+8+18) + (size_t)NN*(1+6+3+6+1+6+18) + 1536 + 12288)*4
                       + ((size_t)NN*3 + 1 + (size_t)NE*2)*4;

    if (ws_size >= need_sorted){
        float* p = (float*)d_ws;
        float* nhat_s  = p; p += (size_t)NE*3;
        float* radial_s= p; p += (size_t)NE*8;
        float* msg     = p; p += (size_t)NE*18;
        float* s       = p; p += NN;
        float* v       = p; p += NN*6;
        float* s_sc    = p; p += NN*3;
        float* v_sc    = p; p += NN*6;
        float* su      = p; p += NN;
        float* vu      = p; p += NN*6;
        float* agg     = p; p += NN*18;
        float* W1T     = p; p += 1536;
        float* W2T     = p; p += 12288;
        int* ip = (int*)p;
        int* cnt    = ip; ip += NN;
        int* rowptr = ip; ip += NN+1;
        int* wcur   = ip; ip += NN;
        int* slot   = ip; ip += NE;
        int* snd_s  = ip; ip += NE;

        transpose_w<<<dim3((3*4096+255)/256), blk, 0, stream>>>(W1, W2, W1T, W2T);
        hipMemsetAsync(cnt, 0, NN*sizeof(int), stream);
        hist_rcv<<<gE, blk, 0, stream>>>(rcv, cnt);
        exscan<<<dim3(1), dim3(1024), 0, stream>>>(cnt, rowptr, wcur);
        scatter_edges<<<gE, blk, 0, stream>>>(snd, rcv, wcur, slot, snd_s);
        edge_geom<<<gE, blk, 0, stream>>>(pos, snd, rcv, slot, nhat_s, radial_s);
        node_init<<<gN, blk, 0, stream>>>(nf, s, v);
        for (int l=0;l<3;l++){
            node_pre<<<gN, blk, 0, stream>>>(
                s, v, Wss+l*3, Wsv+l*4, Wus+l, Wuv+l*4, s_sc, v_sc, su, vu);
            edge_msg2<<<gE, blk, 0, stream>>>(
                snd_s, nhat_s, radial_s, su, vu,
                W1T+l*512, W2T+l*4096, W3+l*512, msg);
            agg18<<<dim3((NN*18+255)/256), blk, 0, stream>>>(msg, rowptr, agg);
            node_post18<<<gN, blk, 0, stream>>>(
                agg, Wds+l*9, Wdv+l*10, s_sc, v_sc, s, v, out, (l==2)?1:0);
        }
    } else {
        float* p = (float*)d_ws;
        float* nhat   = p; p += (size_t)NE*3;
        float* radial = p; p += (size_t)NE*8;
        float* s      = p; p += NN;
        float* v      = p; p += NN*6;
        float* s_sc   = p; p += NN*3;
        float* v_sc   = p; p += NN*6;
        float* su     = p; p += NN;
        float* vu     = p; p += NN*6;
        float* aggs   = p; p += NN*3;
        float* aggv   = p; p += NN*15;
        float* W1T    = p; p += 1536;
        float* W2T    = p; p += 12288;

        transpose_w<<<dim3((3*4096+255)/256), blk, 0, stream>>>(W1, W2, W1T, W2T);
        edge_geom<<<gE, blk, 0, stream>>>(pos, snd, rcv, nullptr, nhat, radial);
        node_init<<<gN, blk, 0, stream>>>(nf, s, v);
        for (int l=0;l<3;l++){
            node_pre<<<gN, blk, 0, stream>>>(
                s, v, Wss+l*3, Wsv+l*4, Wus+l, Wuv+l*4, s_sc, v_sc, su, vu);
            hipMemsetAsync(aggs, 0, NN*3*sizeof(float), stream);
            hipMemsetAsync(aggv, 0, NN*15*sizeof(float), stream);
            edge_msg_atomic<<<gE, blk, 0, stream>>>(
                snd, rcv, nhat, radial, su, vu,
                W1T+l*512, W2T+l*4096, W3+l*512, aggs, aggv);
            node_post_split<<<gN, blk, 0, stream>>>(
                aggs, aggv, Wds+l*9, Wdv+l*10, s_sc, v_sc, s, v, out, (l==2)?1:0);
        }
    }
}